// Round 2
// baseline (843.512 us; speedup 1.0000x reference)
//
#include <hip/hip_runtime.h>
#include <stdint.h>

typedef __attribute__((ext_vector_type(8))) short short8;
typedef __attribute__((ext_vector_type(4))) float f32x4;

#define TT 512
#define LSTR 136   // sZ row stride in ushorts: 272B -> spread banks
#define XS 516     // sX row stride in floats

static __device__ __forceinline__ uint32_t f2bf_u(float f){
  union { float f; uint32_t u; } v; v.f = f;
  return (v.u + 0x7fffu + ((v.u >> 16) & 1u)) >> 16;
}
static __device__ __forceinline__ short8 w8f32(const float* p){
  float4 a = *(const float4*)p;
  float4 b = *(const float4*)(p + 4);
  short8 r;
  r[0] = (short)f2bf_u(a.x); r[1] = (short)f2bf_u(a.y);
  r[2] = (short)f2bf_u(a.z); r[3] = (short)f2bf_u(a.w);
  r[4] = (short)f2bf_u(b.x); r[5] = (short)f2bf_u(b.y);
  r[6] = (short)f2bf_u(b.z); r[7] = (short)f2bf_u(b.w);
  return r;
}
// sigmoid via exp2+rcp: 4 ops, 2 trans. Inf-safe (exp2->inf => rcp->0).
static __device__ __forceinline__ float sigx(float x){
  float e = __builtin_amdgcn_exp2f(-1.442695040888963f * x);
  return __builtin_amdgcn_rcpf(1.f + e);
}
// tanh(x) = 2*sigmoid(2x)-1: 5 ops, 2 trans, no clamp needed.
static __device__ __forceinline__ float tanhx(float x){
  float e = __builtin_amdgcn_exp2f(-2.885390081777927f * x);
  return fmaf(__builtin_amdgcn_rcpf(1.f + e), 2.f, -1.f);
}
// LDS-only barrier: waits ds ops, leaves global loads/stores in flight.
static __device__ __forceinline__ void lds_barrier(){
  asm volatile("s_waitcnt lgkmcnt(0)" ::: "memory");
  __builtin_amdgcn_s_barrier();
}
#define MF(A,B,C) __builtin_amdgcn_mfma_f32_16x16x32_bf16((A),(B),(C),0,0,0)

// Redistributed nonlinearity. ds_swizzle (lane^8) is CONVERGENT: it must run
// with all lanes active, so the 4 swizzles are unconditional top-level
// statements; the select happens afterwards on register values (v_cndmask).
// Lanes m16<8 use own a0 (unit u0); lanes m16>=8 use partner's a1 (unit u1).
#define NONLIN_WRITE(A0V, A1V, P1) do { \
    float s0_ = __int_as_float(__builtin_amdgcn_ds_swizzle(__float_as_int((A1V)[0]), 0x201F)); \
    float s1_ = __int_as_float(__builtin_amdgcn_ds_swizzle(__float_as_int((A1V)[1]), 0x201F)); \
    float s2_ = __int_as_float(__builtin_amdgcn_ds_swizzle(__float_as_int((A1V)[2]), 0x201F)); \
    float s3_ = __int_as_float(__builtin_amdgcn_ds_swizzle(__float_as_int((A1V)[3]), 0x201F)); \
    float g0_ = sel0 ? (A0V)[0] : s0_; \
    float g1_ = sel0 ? (A0V)[1] : s1_; \
    float g2_ = sel0 ? (A0V)[2] : s2_; \
    float g3_ = sel0 ? (A0V)[3] : s3_; \
    float ii_ = sigx(g0_), ff_ = sigx(g1_), gg_ = tanhx(g2_), oo_ = sigx(g3_); \
    c = fmaf(ff_, c, ii_ * gg_); \
    h = oo_ * tanhx(c); \
    { union { float f; uint32_t u; } hv_; hv_.f = h; \
      uint32_t r_ = hv_.u + 0x7fffu + ((hv_.u >> 16) & 1u); \
      union { uint32_t u; float f; } hi_; hi_.u = r_ & 0xffff0000u; \
      union { float f; uint32_t u; } lv_; lv_.f = h - hi_.f; \
      sZ[P1][rw][colw]      = (unsigned short)(r_ >> 16); \
      sZ[P1][rw][64 + colw] = (unsigned short)(lv_.u >> 16); } \
  } while(0)

// ==================== Layer 0 ====================
// 512 thr / 8 waves; wave w owns rowtiles 2w,2w+1 (units 8w+q, 8w+4+q per lane quad q)
__global__ __launch_bounds__(512, 2) void lstm_l0(
    const float* __restrict__ x,   // [B][3][T]
    const float* __restrict__ Wih_f, const float* __restrict__ Whh_f,
    const float* __restrict__ bih_f, const float* __restrict__ bhh_f,
    const float* __restrict__ Wih_b, const float* __restrict__ Whh_b,
    const float* __restrict__ bih_b, const float* __restrict__ bhh_b,
    unsigned short* __restrict__ y0)  // [B][T][128] bf16
{
  const int tid = threadIdx.x;
  const int wv = tid >> 6, lane = tid & 63;
  const int quad = lane >> 4, m16 = lane & 15;
  const int dir = blockIdx.y;
  const int bbase = blockIdx.x * 8;
  const float* Wih = dir ? Wih_b : Wih_f;
  const float* Whh = dir ? Whh_b : Whh_f;
  const float* bih = dir ? bih_b : bih_f;
  const float* bhh = dir ? bhh_b : bhh_f;

  __shared__ __align__(16) unsigned short sZ[2][16][LSTR];
  __shared__ __align__(16) float sX[24 * XS];

  // A-frags: tile-row rho -> gate (rho&3), unit 4*rt+(rho>>2). Lane's A row: rho=m16, k=quad*8+j.
  short8 aH[2][2], aX[2];
  f32x4 biasv[2];
  const int gm = (m16 & 3) * 64 + (m16 >> 2);
  #pragma unroll
  for (int i = 0; i < 2; i++){
    const int rt = 2 * wv + i;
    const int g = gm + 4 * rt;
    aH[i][0] = w8f32(Whh + g * 64 + quad * 8);
    aH[i][1] = w8f32(Whh + g * 64 + 32 + quad * 8);
    short8 ax = {0,0,0,0,0,0,0,0};
    if (quad == 0){
      ax[0] = (short)f2bf_u(Wih[g * 3 + 0]);
      ax[1] = (short)f2bf_u(Wih[g * 3 + 1]);
      ax[2] = (short)f2bf_u(Wih[g * 3 + 2]);
    }
    aX[i] = ax;
    const int gu = 4 * rt + quad;   // C reg r -> gate row r*64 + gu
    #pragma unroll
    for (int r = 0; r < 4; r++) biasv[i][r] = bih[r * 64 + gu] + bhh[r * 64 + gu];
  }

  for (int idx = tid; idx < 2 * 16 * LSTR; idx += 512)
    ((unsigned short*)sZ)[idx] = 0;
  for (int i4 = tid; i4 < 3072; i4 += 512){
    const int row = i4 >> 7, t4 = (i4 & 127) * 4;
    *(float4*)&sX[row * XS + t4] = *(const float4*)(x + (size_t)bbase * 1536 + row * 512 + t4);
  }
  __syncthreads();

  const int xrow = 3 * (m16 & 7);
  const bool sel0 = (m16 < 8);
  const int rw = m16 & 7;
  const int colw = 8 * wv + quad + ((m16 >> 3) << 2);  // u0 for m16<8, u1 for m16>=8
  float c = 0.f, h = 0.f;
  const f32x4 z4 = {0.f, 0.f, 0.f, 0.f};

#define L0STEP(S, P) do { \
    const int t_ = dir ? (TT - 1 - (S)) : (S); \
    short8 bh0 = *(const short8*)&sZ[P][m16][     quad * 8]; \
    short8 bh1 = *(const short8*)&sZ[P][m16][32 + quad * 8]; \
    short8 bl0 = *(const short8*)&sZ[P][m16][64 + quad * 8]; \
    short8 bl1 = *(const short8*)&sZ[P][m16][96 + quad * 8]; \
    short8 bx = {0,0,0,0,0,0,0,0}; \
    if (quad == 0){ \
      bx[0] = (short)f2bf_u(sX[xrow * XS + t_]); \
      bx[1] = (short)f2bf_u(sX[(xrow + 1) * XS + t_]); \
      bx[2] = (short)f2bf_u(sX[(xrow + 2) * XS + t_]); \
    } \
    if (wv == 7 && (S) > 0){ \
      const int tprev = dir ? (TT - (S)) : ((S) - 1); \
      const int br_ = lane >> 3, cc_ = lane & 7; \
      short8 v_ = *(const short8*)&sZ[P][br_][cc_ * 8]; \
      *(short8*)(y0 + ((size_t)(bbase + br_) * TT + tprev) * 128 + dir * 64 + cc_ * 8) = v_; \
    } \
    f32x4 A0 = MF(aH[0][0], bh0, biasv[0]); \
    f32x4 A1 = MF(aH[1][0], bh0, biasv[1]); \
    A0 = MF(aH[0][1], bh1, A0);  A1 = MF(aH[1][1], bh1, A1); \
    f32x4 B0 = MF(aH[0][0], bl0, z4); \
    f32x4 B1 = MF(aH[1][0], bl0, z4); \
    B0 = MF(aH[0][1], bl1, B0);  B1 = MF(aH[1][1], bl1, B1); \
    B0 = MF(aX[0], bx, B0);      B1 = MF(aX[1], bx, B1); \
    f32x4 a0_ = A0 + B0, a1_ = A1 + B1; \
    NONLIN_WRITE(a0_, a1_, (1 - (P))); \
    lds_barrier(); \
  } while(0)

  for (int s = 0; s < TT; s += 2){
    L0STEP(s, 0);
    L0STEP(s + 1, 1);
  }
#undef L0STEP

  // final timestep's h (last write went to sZ[0])
  if (wv == 7){
    const int tl = dir ? 0 : (TT - 1);
    const int br = lane >> 3, cc = lane & 7;
    short8 v = *(const short8*)&sZ[0][br][cc * 8];
    *(short8*)(y0 + ((size_t)(bbase + br) * TT + tl) * 128 + dir * 64 + cc * 8) = v;
  }
}

// ==================== Layer 1 ====================
// y-fragments loaded straight from global (no sY LDS stage), 2-step reg prefetch.
__global__ __launch_bounds__(512, 2) void lstm_l1(
    const unsigned short* __restrict__ y0,  // [B][T][128] bf16
    const float* __restrict__ Wih_f, const float* __restrict__ Whh_f,
    const float* __restrict__ bih_f, const float* __restrict__ bhh_f,
    const float* __restrict__ Wih_b, const float* __restrict__ Whh_b,
    const float* __restrict__ bih_b, const float* __restrict__ bhh_b,
    float* __restrict__ hT)                 // [B][128] fp32
{
  const int tid = threadIdx.x;
  const int wv = tid >> 6, lane = tid & 63;
  const int quad = lane >> 4, m16 = lane & 15;
  const int dir = blockIdx.y;
  const int bbase = blockIdx.x * 8;
  const float* Wih = dir ? Wih_b : Wih_f;
  const float* Whh = dir ? Whh_b : Whh_f;
  const float* bih = dir ? bih_b : bih_f;
  const float* bhh = dir ? bhh_b : bhh_f;

  __shared__ __align__(16) unsigned short sZ[2][16][LSTR];

  short8 aY[2][4], aH[2][2];
  f32x4 biasv[2];
  const int gm = (m16 & 3) * 64 + (m16 >> 2);
  #pragma unroll
  for (int i = 0; i < 2; i++){
    const int rt = 2 * wv + i;
    const int g = gm + 4 * rt;
    #pragma unroll
    for (int kt = 0; kt < 4; kt++) aY[i][kt] = w8f32(Wih + g * 128 + kt * 32 + quad * 8);
    aH[i][0] = w8f32(Whh + g * 64 + quad * 8);
    aH[i][1] = w8f32(Whh + g * 64 + 32 + quad * 8);
    const int gu = 4 * rt + quad;
    #pragma unroll
    for (int r = 0; r < 4; r++) biasv[i][r] = bih[r * 64 + gu] + bhh[r * 64 + gu];
  }

  for (int idx = tid; idx < 2 * 16 * LSTR; idx += 512)
    ((unsigned short*)sZ)[idx] = 0;
  __syncthreads();

  const bool sel0 = (m16 < 8);
  const int rw = m16 & 7;
  const int colw = 8 * wv + quad + ((m16 >> 3) << 2);
  float c = 0.f, h = 0.f;
  const f32x4 z4 = {0.f, 0.f, 0.f, 0.f};

  // per-lane y fragment base: batch row (dup'd for pad cols), k = quad*8
  const unsigned short* yq = y0 + (size_t)(bbase + rw) * TT * 128 + quad * 8;

#define LOADY(BY, S) do { \
    int sg_ = (S); if (sg_ > TT - 1) sg_ = TT - 1; \
    const int tg_ = dir ? (TT - 1 - sg_) : sg_; \
    const unsigned short* p_ = yq + (size_t)tg_ * 128; \
    BY##0 = *(const short8*)(p_); \
    BY##1 = *(const short8*)(p_ + 32); \
    BY##2 = *(const short8*)(p_ + 64); \
    BY##3 = *(const short8*)(p_ + 96); \
  } while(0)

  short8 byA0, byA1, byA2, byA3, byB0, byB1, byB2, byB3;
  LOADY(byA, 0);
  LOADY(byB, 1);

#define L1STEP(S, P, BY) do { \
    short8 bh0 = *(const short8*)&sZ[P][m16][     quad * 8]; \
    short8 bh1 = *(const short8*)&sZ[P][m16][32 + quad * 8]; \
    short8 bl0 = *(const short8*)&sZ[P][m16][64 + quad * 8]; \
    short8 bl1 = *(const short8*)&sZ[P][m16][96 + quad * 8]; \
    f32x4 A0 = MF(aY[0][0], BY##0, biasv[0]); \
    f32x4 A1 = MF(aY[1][0], BY##0, biasv[1]); \
    A0 = MF(aY[0][1], BY##1, A0);  A1 = MF(aY[1][1], BY##1, A1); \
    f32x4 B0 = MF(aY[0][2], BY##2, z4); \
    f32x4 B1 = MF(aY[1][2], BY##2, z4); \
    B0 = MF(aY[0][3], BY##3, B0);  B1 = MF(aY[1][3], BY##3, B1); \
    A0 = MF(aH[0][0], bh0, A0);    A1 = MF(aH[1][0], bh0, A1); \
    A0 = MF(aH[0][1], bh1, A0);    A1 = MF(aH[1][1], bh1, A1); \
    B0 = MF(aH[0][0], bl0, B0);    B1 = MF(aH[1][0], bl0, B1); \
    B0 = MF(aH[0][1], bl1, B0);    B1 = MF(aH[1][1], bl1, B1); \
    LOADY(BY, (S) + 2); \
    f32x4 a0_ = A0 + B0, a1_ = A1 + B1; \
    NONLIN_WRITE(a0_, a1_, (1 - (P))); \
    lds_barrier(); \
  } while(0)

  for (int s = 0; s < TT; s += 2){
    L1STEP(s, 0, byA);
    L1STEP(s + 1, 1, byB);
  }
#undef L1STEP
#undef LOADY

  // final h: every lane holds one real (batch rw, unit colw) value
  hT[(size_t)(bbase + rw) * 128 + dir * 64 + colw] = h;
}

// ==================== FC head ====================
__global__ __launch_bounds__(256, 1) void fc_kernel(
    const float* __restrict__ hT,
    const float* __restrict__ w1, const float* __restrict__ b1,
    const float* __restrict__ w2, const float* __restrict__ b2,
    float* __restrict__ out)
{
  __shared__ float sh[4][64];
  const int wave = threadIdx.x >> 6, lane = threadIdx.x & 63;
  const int b = blockIdx.x * 4 + wave;
  float acc = b1[lane];
  const float* hrow = hT + (size_t)b * 128;
  #pragma unroll
  for (int k = 0; k < 128; k += 4){
    float4 h4 = *(const float4*)(hrow + k);
    float4 w4 = *(const float4*)(w1 + lane * 128 + k);
    acc = fmaf(w4.x, h4.x, acc);
    acc = fmaf(w4.y, h4.y, acc);
    acc = fmaf(w4.z, h4.z, acc);
    acc = fmaf(w4.w, h4.w, acc);
  }
  sh[wave][lane] = fmaxf(acc, 0.f);
  __syncthreads();
  if (lane < 2){
    float a = b2[lane];
    #pragma unroll
    for (int k = 0; k < 64; k++) a = fmaf(w2[lane * 64 + k], sh[wave][k], a);
    out[(size_t)b * 2 + lane] = a;
  }
}

extern "C" void kernel_launch(void* const* d_in, const int* in_sizes, int n_in,
                              void* d_out, int out_size, void* d_ws, size_t ws_size,
                              hipStream_t stream){
  (void)in_sizes; (void)n_in; (void)out_size; (void)ws_size;
  const float* x     = (const float*)d_in[0];
  const float* Wih0f = (const float*)d_in[1];
  const float* Whh0f = (const float*)d_in[2];
  const float* bih0f = (const float*)d_in[3];
  const float* bhh0f = (const float*)d_in[4];
  const float* Wih0b = (const float*)d_in[5];
  const float* Whh0b = (const float*)d_in[6];
  const float* bih0b = (const float*)d_in[7];
  const float* bhh0b = (const float*)d_in[8];
  const float* Wih1f = (const float*)d_in[9];
  const float* Whh1f = (const float*)d_in[10];
  const float* bih1f = (const float*)d_in[11];
  const float* bhh1f = (const float*)d_in[12];
  const float* Wih1b = (const float*)d_in[13];
  const float* Whh1b = (const float*)d_in[14];
  const float* bih1b = (const float*)d_in[15];
  const float* bhh1b = (const float*)d_in[16];
  const float* fc1W  = (const float*)d_in[17];
  const float* fc1b  = (const float*)d_in[18];
  const float* fc2W  = (const float*)d_in[19];
  const float* fc2b  = (const float*)d_in[20];
  float* out = (float*)d_out;

  unsigned short* y0 = (unsigned short*)d_ws;                       // 134,217,728 B
  float* hT = (float*)((char*)d_ws + (size_t)1024 * TT * 128 * 2);

  dim3 grid(128, 2), block(512);
  lstm_l0<<<grid, block, 0, stream>>>(x, Wih0f, Whh0f, bih0f, bhh0f,
                                      Wih0b, Whh0b, bih0b, bhh0b, y0);
  lstm_l1<<<grid, block, 0, stream>>>(y0, Wih1f, Whh1f, bih1f, bhh1f,
                                      Wih1b, Whh1b, bih1b, bhh1b, hT);
  fc_kernel<<<dim3(256), dim3(256), 0, stream>>>(hT, fc1W, fc1b, fc2W, fc2b, out);
}

// Round 3
// 649.449 us; speedup vs baseline: 1.2988x; 1.2988x over previous
//
#include <hip/hip_runtime.h>
#include <stdint.h>

typedef __attribute__((ext_vector_type(8))) short short8;
typedef __attribute__((ext_vector_type(4))) float f32x4;

#define TT 512
#define LSTR 136   // sZ/sY row stride in ushorts: 272B -> spread banks
#define XS 516     // sX row stride in floats

static __device__ __forceinline__ uint32_t f2bf_u(float f){
  union { float f; uint32_t u; } v; v.f = f;
  return (v.u + 0x7fffu + ((v.u >> 16) & 1u)) >> 16;
}
static __device__ __forceinline__ short8 w8f32(const float* p){
  float4 a = *(const float4*)p;
  float4 b = *(const float4*)(p + 4);
  short8 r;
  r[0] = (short)f2bf_u(a.x); r[1] = (short)f2bf_u(a.y);
  r[2] = (short)f2bf_u(a.z); r[3] = (short)f2bf_u(a.w);
  r[4] = (short)f2bf_u(b.x); r[5] = (short)f2bf_u(b.y);
  r[6] = (short)f2bf_u(b.z); r[7] = (short)f2bf_u(b.w);
  return r;
}
// 4 Whh columns, each duplicated into an adjacent bf16 pair: multiplies the
// interleaved (hi,lo) k-layout of sZ.
static __device__ __forceinline__ short8 w8dup(const float* p){
  float4 a = *(const float4*)p;
  short w0 = (short)f2bf_u(a.x), w1 = (short)f2bf_u(a.y);
  short w2 = (short)f2bf_u(a.z), w3 = (short)f2bf_u(a.w);
  short8 r;
  r[0] = w0; r[1] = w0; r[2] = w1; r[3] = w1;
  r[4] = w2; r[5] = w2; r[6] = w3; r[7] = w3;
  return r;
}
// sigmoid via exp2+rcp: inf-safe (exp2->inf => rcp->0).
static __device__ __forceinline__ float sigx(float x){
  float e = __builtin_amdgcn_exp2f(-1.442695040888963f * x);
  return __builtin_amdgcn_rcpf(1.f + e);
}
// tanh(x) = 2*sigmoid(2x)-1: no clamp needed.
static __device__ __forceinline__ float tanhx(float x){
  float e = __builtin_amdgcn_exp2f(-2.885390081777927f * x);
  return fmaf(__builtin_amdgcn_rcpf(1.f + e), 2.f, -1.f);
}
// LDS-only barrier: waits ds ops, leaves global loads/stores in flight.
static __device__ __forceinline__ void lds_barrier(){
  asm volatile("s_waitcnt lgkmcnt(0)" ::: "memory");
  __builtin_amdgcn_s_barrier();
}
#define MF(A,B,C) __builtin_amdgcn_mfma_f32_16x16x32_bf16((A),(B),(C),0,0,0)

// Redistributed nonlinearity, swizzle-free: sZ rows 8-15 duplicate rows 0-7,
// so MFMA C cols 8-15 hold real (dup) batch data and lanes m16>=8 use their
// own a1 registers (v_cndmask select). Each lane handles ONE (batch,unit)
// quad. h stored as packed (hi | lo<<16) word at [rw][2*colw] and [rw+8][..].
#define NONLIN_WRITE(A0V, A1V, P1) do { \
    float g0_ = sel0 ? (A0V)[0] : (A1V)[0]; \
    float g1_ = sel0 ? (A0V)[1] : (A1V)[1]; \
    float g2_ = sel0 ? (A0V)[2] : (A1V)[2]; \
    float g3_ = sel0 ? (A0V)[3] : (A1V)[3]; \
    float ii_ = sigx(g0_), ff_ = sigx(g1_), gg_ = tanhx(g2_), oo_ = sigx(g3_); \
    c = fmaf(ff_, c, ii_ * gg_); \
    h = oo_ * tanhx(c); \
    { union { float f; uint32_t u; } hv_; hv_.f = h; \
      uint32_t r_ = hv_.u + 0x7fffu + ((hv_.u >> 16) & 1u); \
      union { uint32_t u; float f; } hi_; hi_.u = r_ & 0xffff0000u; \
      union { float f; uint32_t u; } lv_; lv_.f = h - hi_.f; \
      uint32_t pk_ = (r_ >> 16) | (lv_.u & 0xffff0000u); \
      *(uint32_t*)&sZ[P1][rw][2 * colw]     = pk_; \
      *(uint32_t*)&sZ[P1][rw + 8][2 * colw] = pk_; } \
  } while(0)

// ==================== Layer 0 ====================
// 512 thr / 8 waves; wave w owns rowtiles 2w,2w+1 (units 8w+q, 8w+4+q per lane quad q)
__global__ __launch_bounds__(512, 2) void lstm_l0(
    const float* __restrict__ x,   // [B][3][T]
    const float* __restrict__ Wih_f, const float* __restrict__ Whh_f,
    const float* __restrict__ bih_f, const float* __restrict__ bhh_f,
    const float* __restrict__ Wih_b, const float* __restrict__ Whh_b,
    const float* __restrict__ bih_b, const float* __restrict__ bhh_b,
    unsigned short* __restrict__ y0)  // [B][T][128] bf16
{
  const int tid = threadIdx.x;
  const int wv = tid >> 6, lane = tid & 63;
  const int quad = lane >> 4, m16 = lane & 15;
  const int dir = blockIdx.y;
  const int bbase = blockIdx.x * 8;
  const float* Wih = dir ? Wih_b : Wih_f;
  const float* Whh = dir ? Whh_b : Whh_f;
  const float* bih = dir ? bih_b : bih_f;
  const float* bhh = dir ? bhh_b : bhh_f;

  __shared__ __align__(16) unsigned short sZ[2][16][LSTR];
  __shared__ __align__(16) float sX[24 * XS];

  // A-frags. sZ k-layout: ushort 2u = hi(h_u), 2u+1 = lo(h_u). MFMA m covers
  // units 16m..16m+15; lane (quad) k=quad*8+j -> unit 16m+quad*4+(j>>1).
  short8 aH[2][4], aX[2];
  f32x4 biasv[2];
  const int gm = (m16 & 3) * 64 + (m16 >> 2);
  #pragma unroll
  for (int i = 0; i < 2; i++){
    const int rt = 2 * wv + i;
    const int g = gm + 4 * rt;
    #pragma unroll
    for (int m = 0; m < 4; m++) aH[i][m] = w8dup(Whh + g * 64 + m * 16 + quad * 4);
    short8 ax = {0,0,0,0,0,0,0,0};
    if (quad == 0){
      ax[0] = (short)f2bf_u(Wih[g * 3 + 0]);
      ax[1] = (short)f2bf_u(Wih[g * 3 + 1]);
      ax[2] = (short)f2bf_u(Wih[g * 3 + 2]);
    }
    aX[i] = ax;
    const int gu = 4 * rt + quad;   // C reg r -> gate row r*64 + gu
    #pragma unroll
    for (int r = 0; r < 4; r++) biasv[i][r] = bih[r * 64 + gu] + bhh[r * 64 + gu];
  }

  for (int idx = tid; idx < 2 * 16 * LSTR; idx += 512)
    ((unsigned short*)sZ)[idx] = 0;
  for (int i4 = tid; i4 < 3072; i4 += 512){
    const int row = i4 >> 7, t4 = (i4 & 127) * 4;
    *(float4*)&sX[row * XS + t4] = *(const float4*)(x + (size_t)bbase * 1536 + row * 512 + t4);
  }
  __syncthreads();

  const int xrow = 3 * (m16 & 7);
  const bool sel0 = (m16 < 8);
  const int rw = m16 & 7;
  const int colw = 8 * wv + quad + ((m16 >> 3) << 2);  // u0 for m16<8, u1 for m16>=8
  float c = 0.f, h = 0.f;
  const f32x4 z4 = {0.f, 0.f, 0.f, 0.f};

#define L0STEP(S, P) do { \
    const int t_ = dir ? (TT - 1 - (S)) : (S); \
    short8 b0 = *(const short8*)&sZ[P][m16][     quad * 8]; \
    short8 b1 = *(const short8*)&sZ[P][m16][32 + quad * 8]; \
    short8 b2 = *(const short8*)&sZ[P][m16][64 + quad * 8]; \
    short8 b3 = *(const short8*)&sZ[P][m16][96 + quad * 8]; \
    short8 bx = {0,0,0,0,0,0,0,0}; \
    if (quad == 0){ \
      bx[0] = (short)f2bf_u(sX[xrow * XS + t_]); \
      bx[1] = (short)f2bf_u(sX[(xrow + 1) * XS + t_]); \
      bx[2] = (short)f2bf_u(sX[(xrow + 2) * XS + t_]); \
    } \
    if (wv == 7 && (S) > 0){ \
      const int tprev = dir ? (TT - (S)) : ((S) - 1); \
      const int br_ = lane >> 3, cc_ = lane & 7; \
      const uint32_t* wp_ = (const uint32_t*)&sZ[P][br_][16 * cc_]; \
      uint4 wa_ = *(const uint4*)(wp_); \
      uint4 wb_ = *(const uint4*)(wp_ + 4); \
      uint4 o_; \
      o_.x = (wa_.x & 0xffffu) | (wa_.y << 16); \
      o_.y = (wa_.z & 0xffffu) | (wa_.w << 16); \
      o_.z = (wb_.x & 0xffffu) | (wb_.y << 16); \
      o_.w = (wb_.z & 0xffffu) | (wb_.w << 16); \
      *(uint4*)(y0 + ((size_t)(bbase + br_) * TT + tprev) * 128 + dir * 64 + cc_ * 8) = o_; \
    } \
    f32x4 A0 = MF(aH[0][0], b0, biasv[0]); \
    f32x4 A1 = MF(aH[1][0], b0, biasv[1]); \
    A0 = MF(aH[0][1], b1, A0);  A1 = MF(aH[1][1], b1, A1); \
    f32x4 B0 = MF(aX[0], bx, z4); \
    f32x4 B1 = MF(aX[1], bx, z4); \
    B0 = MF(aH[0][2], b2, B0);  B1 = MF(aH[1][2], b2, B1); \
    B0 = MF(aH[0][3], b3, B0);  B1 = MF(aH[1][3], b3, B1); \
    f32x4 a0_ = A0 + B0, a1_ = A1 + B1; \
    NONLIN_WRITE(a0_, a1_, (1 - (P))); \
    lds_barrier(); \
  } while(0)

  for (int s = 0; s < TT; s += 2){
    L0STEP(s, 0);
    L0STEP(s + 1, 1);
  }
#undef L0STEP

  // final timestep's h (last write went to sZ[0])
  if (wv == 7){
    const int tl = dir ? 0 : (TT - 1);
    const int br = lane >> 3, cc = lane & 7;
    const uint32_t* wp = (const uint32_t*)&sZ[0][br][16 * cc];
    uint4 wa = *(const uint4*)(wp);
    uint4 wb = *(const uint4*)(wp + 4);
    uint4 o;
    o.x = (wa.x & 0xffffu) | (wa.y << 16);
    o.y = (wa.z & 0xffffu) | (wa.w << 16);
    o.z = (wb.x & 0xffffu) | (wb.y << 16);
    o.w = (wb.z & 0xffffu) | (wb.w << 16);
    *(uint4*)(y0 + ((size_t)(bbase + br) * TT + tl) * 128 + dir * 64 + cc * 8) = o;
  }
}

// ==================== Layer 1 ====================
// y0 staged through a 4-slot LDS ring by waves 0-1 (load once, share via LDS).
__global__ __launch_bounds__(512, 2) void lstm_l1(
    const unsigned short* __restrict__ y0,  // [B][T][128] bf16
    const float* __restrict__ Wih_f, const float* __restrict__ Whh_f,
    const float* __restrict__ bih_f, const float* __restrict__ bhh_f,
    const float* __restrict__ Wih_b, const float* __restrict__ Whh_b,
    const float* __restrict__ bih_b, const float* __restrict__ bhh_b,
    float* __restrict__ hT)                 // [B][128] fp32
{
  const int tid = threadIdx.x;
  const int wv = tid >> 6, lane = tid & 63;
  const int quad = lane >> 4, m16 = lane & 15;
  const int dir = blockIdx.y;
  const int bbase = blockIdx.x * 8;
  const float* Wih = dir ? Wih_b : Wih_f;
  const float* Whh = dir ? Whh_b : Whh_f;
  const float* bih = dir ? bih_b : bih_f;
  const float* bhh = dir ? bhh_b : bhh_f;

  __shared__ __align__(16) unsigned short sZ[2][16][LSTR];
  __shared__ __align__(16) unsigned short sY[4][8][LSTR];   // 4-slot y0 ring

  short8 aY[2][4], aH[2][4];
  f32x4 biasv[2];
  const int gm = (m16 & 3) * 64 + (m16 >> 2);
  #pragma unroll
  for (int i = 0; i < 2; i++){
    const int rt = 2 * wv + i;
    const int g = gm + 4 * rt;
    #pragma unroll
    for (int kt = 0; kt < 4; kt++) aY[i][kt] = w8f32(Wih + g * 128 + kt * 32 + quad * 8);
    #pragma unroll
    for (int m = 0; m < 4; m++) aH[i][m] = w8dup(Whh + g * 64 + m * 16 + quad * 4);
    const int gu = 4 * rt + quad;
    #pragma unroll
    for (int r = 0; r < 4; r++) biasv[i][r] = bih[r * 64 + gu] + bhh[r * 64 + gu];
  }

  for (int idx = tid; idx < 2 * 16 * LSTR; idx += 512)
    ((unsigned short*)sZ)[idx] = 0;

  // staging lanes (waves 0-1): task = tid in [0,128): row=tid>>4, chunk=tid&15
  const int srow = tid >> 4, schunk = tid & 15;
  const size_t sgbase = (size_t)(bbase + (srow & 7)) * TT * 128 + schunk * 8;
  float4 hA = make_float4(0.f,0.f,0.f,0.f), hB = make_float4(0.f,0.f,0.f,0.f);
  if (wv < 2){
    const int t0 = dir ? (TT-1) : 0, t1 = dir ? (TT-2) : 1, t2 = dir ? (TT-3) : 2;
    const int t3 = dir ? (TT-4) : 3, t4 = dir ? (TT-5) : 4;
    float4 v0 = *(const float4*)(y0 + sgbase + (size_t)t0 * 128);
    float4 v1 = *(const float4*)(y0 + sgbase + (size_t)t1 * 128);
    float4 v2 = *(const float4*)(y0 + sgbase + (size_t)t2 * 128);
    hA = *(const float4*)(y0 + sgbase + (size_t)t3 * 128);
    hB = *(const float4*)(y0 + sgbase + (size_t)t4 * 128);
    *(float4*)&sY[0][srow][schunk * 8] = v0;
    *(float4*)&sY[1][srow][schunk * 8] = v1;
    *(float4*)&sY[2][srow][schunk * 8] = v2;
  }
  __syncthreads();

  const int m8 = m16 & 7;
  const bool sel0 = (m16 < 8);
  const int rw = m16 & 7;
  const int colw = 8 * wv + quad + ((m16 >> 3) << 2);
  float c = 0.f, h = 0.f;
  const f32x4 z4 = {0.f, 0.f, 0.f, 0.f};

#define L1STEP(S, HOLD) do { \
    const int p = (S) & 1, p1 = p ^ 1, slot = (S) & 3; \
    if (wv < 2){ \
      *(float4*)&sY[((S) + 3) & 3][srow][schunk * 8] = HOLD; \
      int sg = (S) + 5; if (sg > TT - 1) sg = TT - 1; \
      const int tg = dir ? (TT - 1 - sg) : sg; \
      HOLD = *(const float4*)(y0 + sgbase + (size_t)tg * 128); \
    } \
    short8 by0 = *(const short8*)&sY[slot][m8][     quad * 8]; \
    short8 by1 = *(const short8*)&sY[slot][m8][32 + quad * 8]; \
    short8 by2 = *(const short8*)&sY[slot][m8][64 + quad * 8]; \
    short8 by3 = *(const short8*)&sY[slot][m8][96 + quad * 8]; \
    short8 bh0 = *(const short8*)&sZ[p][m16][     quad * 8]; \
    short8 bh1 = *(const short8*)&sZ[p][m16][32 + quad * 8]; \
    short8 bh2 = *(const short8*)&sZ[p][m16][64 + quad * 8]; \
    short8 bh3 = *(const short8*)&sZ[p][m16][96 + quad * 8]; \
    f32x4 A0 = MF(aY[0][0], by0, biasv[0]); \
    f32x4 A1 = MF(aY[1][0], by0, biasv[1]); \
    A0 = MF(aY[0][1], by1, A0);  A1 = MF(aY[1][1], by1, A1); \
    f32x4 B0 = MF(aY[0][2], by2, z4); \
    f32x4 B1 = MF(aY[1][2], by2, z4); \
    B0 = MF(aY[0][3], by3, B0);  B1 = MF(aY[1][3], by3, B1); \
    A0 = MF(aH[0][0], bh0, A0);  A1 = MF(aH[1][0], bh0, A1); \
    A0 = MF(aH[0][1], bh1, A0);  A1 = MF(aH[1][1], bh1, A1); \
    B0 = MF(aH[0][2], bh2, B0);  B1 = MF(aH[1][2], bh2, B1); \
    B0 = MF(aH[0][3], bh3, B0);  B1 = MF(aH[1][3], bh3, B1); \
    f32x4 a0_ = A0 + B0, a1_ = A1 + B1; \
    NONLIN_WRITE(a0_, a1_, p1); \
    if ((S) == TT - 1){ \
      hT[(size_t)(bbase + rw) * 128 + dir * 64 + colw] = h; \
    } \
    lds_barrier(); \
  } while(0)

  for (int s = 0; s < TT; s += 2){
    L1STEP(s, hA);
    L1STEP(s + 1, hB);
  }
#undef L1STEP
}

// ==================== FC head ====================
__global__ __launch_bounds__(256, 1) void fc_kernel(
    const float* __restrict__ hT,
    const float* __restrict__ w1, const float* __restrict__ b1,
    const float* __restrict__ w2, const float* __restrict__ b2,
    float* __restrict__ out)
{
  __shared__ float sh[4][64];
  const int wave = threadIdx.x >> 6, lane = threadIdx.x & 63;
  const int b = blockIdx.x * 4 + wave;
  float acc = b1[lane];
  const float* hrow = hT + (size_t)b * 128;
  #pragma unroll
  for (int k = 0; k < 128; k += 4){
    float4 h4 = *(const float4*)(hrow + k);
    float4 w4 = *(const float4*)(w1 + lane * 128 + k);
    acc = fmaf(w4.x, h4.x, acc);
    acc = fmaf(w4.y, h4.y, acc);
    acc = fmaf(w4.z, h4.z, acc);
    acc = fmaf(w4.w, h4.w, acc);
  }
  sh[wave][lane] = fmaxf(acc, 0.f);
  __syncthreads();
  if (lane < 2){
    float a = b2[lane];
    #pragma unroll
    for (int k = 0; k < 64; k++) a = fmaf(w2[lane * 64 + k], sh[wave][k], a);
    out[(size_t)b * 2 + lane] = a;
  }
}

extern "C" void kernel_launch(void* const* d_in, const int* in_sizes, int n_in,
                              void* d_out, int out_size, void* d_ws, size_t ws_size,
                              hipStream_t stream){
  (void)in_sizes; (void)n_in; (void)out_size; (void)ws_size;
  const float* x     = (const float*)d_in[0];
  const float* Wih0f = (const float*)d_in[1];
  const float* Whh0f = (const float*)d_in[2];
  const float* bih0f = (const float*)d_in[3];
  const float* bhh0f = (const float*)d_in[4];
  const float* Wih0b = (const float*)d_in[5];
  const float* Whh0b = (const float*)d_in[6];
  const float* bih0b = (const float*)d_in[7];
  const float* bhh0b = (const float*)d_in[8];
  const float* Wih1f = (const float*)d_in[9];
  const float* Whh1f = (const float*)d_in[10];
  const float* bih1f = (const float*)d_in[11];
  const float* bhh1f = (const float*)d_in[12];
  const float* Wih1b = (const float*)d_in[13];
  const float* Whh1b = (const float*)d_in[14];
  const float* bih1b = (const float*)d_in[15];
  const float* bhh1b = (const float*)d_in[16];
  const float* fc1W  = (const float*)d_in[17];
  const float* fc1b  = (const float*)d_in[18];
  const float* fc2W  = (const float*)d_in[19];
  const float* fc2b  = (const float*)d_in[20];
  float* out = (float*)d_out;

  unsigned short* y0 = (unsigned short*)d_ws;                       // 134,217,728 B
  float* hT = (float*)((char*)d_ws + (size_t)1024 * TT * 128 * 2);

  dim3 grid(128, 2), block(512);
  lstm_l0<<<grid, block, 0, stream>>>(x, Wih0f, Whh0f, bih0f, bhh0f,
                                      Wih0b, Whh0b, bih0b, bhh0b, y0);
  lstm_l1<<<grid, block, 0, stream>>>(y0, Wih1f, Whh1f, bih1f, bhh1f,
                                      Wih1b, Whh1b, bih1b, bhh1b, hT);
  fc_kernel<<<dim3(256), dim3(256), 0, stream>>>(hT, fc1W, fc1b, fc2W, fc2b, out);
}